// Round 8
// baseline (3515.399 us; speedup 1.0000x reference)
//
#include <hip/hip_runtime.h>
#include <stdint.h>

// ---------------- problem constants ----------------
#define NE      16384
#define BATCH   4096
#define DFULL   1024
#define DHALF   512
#define TOPK    10
#define NCHUNK  16
#define CHUNK   1024            // entries per chunk (16384 / 16)
#define CPC     40              // candidates per row per chunk (2 wr * 4 q * 5)
#define NCAND   (NCHUNK * CPC)  // 640 candidates per row
#define MRES    24              // exact-rescore count
#define BETA_C  0.25f

typedef __bf16 bf16x8 __attribute__((ext_vector_type(8)));
typedef float  f32x4  __attribute__((ext_vector_type(4)));

__device__ inline uint16_t f2bf(float f) {
    unsigned u = __float_as_uint(f);
    unsigned r = (u + 0x7FFFu + ((u >> 16) & 1u)) >> 16;
    return (uint16_t)r;
}

__device__ inline float dot4(float4 a, float4 b) {
    return a.x*b.x + a.y*b.y + a.z*b.z + a.w*b.w;
}

// ---------------- normalization kernels ----------------
__global__ __launch_bounds__(256) void k_norm_z(const float* __restrict__ z,
                                                uint16_t* __restrict__ zn,
                                                float* __restrict__ rnzt,
                                                float* __restrict__ rnzg) {
    int b = blockIdx.x, t = threadIdx.x;
    const float4* zp = (const float4*)(z + (size_t)b * DFULL);
    float4 v = zp[t];
    float ss = v.x*v.x + v.y*v.y + v.z*v.z + v.w*v.w;
    #pragma unroll
    for (int off = 32; off; off >>= 1) ss += __shfl_xor(ss, off);
    __shared__ float red[4];
    if ((t & 63) == 0) red[t >> 6] = ss;
    __syncthreads();
    float tot = (t < 128) ? (red[0] + red[1]) : (red[2] + red[3]);
    float rn = rsqrtf(tot + 1e-12f);
    if (t == 0)   rnzt[b] = rn;
    if (t == 128) rnzg[b] = rn;
    uint16_t* o = zn + (size_t)b * DFULL + t * 4;
    o[0] = f2bf(v.x * rn); o[1] = f2bf(v.y * rn);
    o[2] = f2bf(v.z * rn); o[3] = f2bf(v.w * rn);
}

__global__ __launch_bounds__(128) void k_norm_cb(const float* __restrict__ w,
                                                 uint16_t* __restrict__ dst, int dstld,
                                                 float* __restrict__ rns) {
    int r = blockIdx.x, t = threadIdx.x;
    const float4* wp = (const float4*)(w + (size_t)r * DHALF);
    float4 v = wp[t];
    float ss = v.x*v.x + v.y*v.y + v.z*v.z + v.w*v.w;
    #pragma unroll
    for (int off = 32; off; off >>= 1) ss += __shfl_xor(ss, off);
    __shared__ float red[2];
    if ((t & 63) == 0) red[t >> 6] = ss;
    __syncthreads();
    float rn = rsqrtf(red[0] + red[1] + 1e-12f);
    if (t == 0) rns[r] = rn;
    uint16_t* o = dst + (size_t)r * dstld + t * 4;
    o[0] = f2bf(v.x * rn); o[1] = f2bf(v.y * rn);
    o[2] = f2bf(v.z * rn); o[3] = f2bf(v.w * rn);
}

// ---------------- fused GEMM (S^T) + per-lane register top-5 screen ----------
// Block tile: 128 entries x 64 batch, 256 thr = 4 waves. Wave tile 64x32.
// STAGING IS REGISTER-PATH (T14): global_load_dwordx4 -> VGPR -> ds_write_b128.
// R7 evidence: global_load_lds under L2-miss sustains only ~3.3 B/cy/CU
// (shallow LDS-DMA miss queue); per-lane loads use the deep vmem miss queues
// (12 waves x 6KB outstanding/CU). Same pre-swizzled source addresses, same
// linear LDS destinations as before -> LDS contents identical, read path
// unchanged. Barrier now drains only LDS writes; global latency hides under
// the current tile's MFMA+ds_read.
__global__ __launch_bounds__(256, 3) void k_gemm_topk(
    const uint16_t* __restrict__ Zn, int ldz, int zoff,
    const uint16_t* __restrict__ Wn, int ldw, int KT,
    unsigned* __restrict__ cand)
{
    __shared__ uint16_t Wsm[2][128 * 64];   // entries x k, XOR-swizzled 128B rows (32KB)
    __shared__ uint16_t Zsm[2][64 * 64];    // batch   x k (16KB)

    const int tid  = threadIdx.x;
    const int lane = tid & 63;
    const int wv   = tid >> 6;
    const int wr   = wv >> 1;       // entry half (0..1)
    const int wc   = wv & 1;        // batch half (0..1)
    const int q    = lane >> 4;     // k-group / entry row group
    const int c    = lane & 15;
    const int rowbase  = blockIdx.y * 64;      // batch rows
    const int entchunk = blockIdx.x * CHUNK;   // entry base

    // per-thread staging registers (6 x uint4 = 24 VGPR)
    uint4 wr_[4], zr_[2];

    auto LOADG = [&](int cb2, int kt2) {
        const char* Wg = (const char*)(Wn + (size_t)(entchunk + cb2 * 128) * ldw + kt2 * 64);
        const char* Zg = (const char*)(Zn + (size_t)rowbase * ldz + zoff + kt2 * 64);
        #pragma unroll
        for (int it = 0; it < 4; ++it) {            // W: 16KB
            int o = (it * 4 + wv) * 1024 + lane * 16;
            int row = o >> 7;
            int kb  = (o & 127) ^ ((row & 7) << 4); // pre-swizzled source (m173)
            wr_[it] = *(const uint4*)(Wg + (size_t)row * ldw * 2 + kb);
        }
        #pragma unroll
        for (int it = 0; it < 2; ++it) {            // Z: 8KB
            int o = (it * 4 + wv) * 1024 + lane * 16;
            int row = o >> 7;
            int kb  = (o & 127) ^ ((row & 7) << 4);
            zr_[it] = *(const uint4*)(Zg + (size_t)row * ldz * 2 + kb);
        }
    };
    auto WRITES = [&](int bufi) {
        char* Wd = (char*)&Wsm[bufi][0];
        char* Zd = (char*)&Zsm[bufi][0];
        #pragma unroll
        for (int it = 0; it < 4; ++it)
            *(uint4*)(Wd + (it * 4 + wv) * 1024 + lane * 16) = wr_[it];
        #pragma unroll
        for (int it = 0; it < 2; ++it)
            *(uint4*)(Zd + (it * 4 + wv) * 1024 + lane * 16) = zr_[it];
    };

    // per-lane sorted lists (descending), packed (sortable16(v)<<16)|entry_idx
    unsigned L0[2] = {0,0}, L1[2] = {0,0}, L2[2] = {0,0},
             L3[2] = {0,0}, L4[2] = {0,0};

    LOADG(0, 0);
    WRITES(0);
    __syncthreads();
    int cur = 0;

    for (int cb = 0; cb < 8; ++cb) {
        f32x4 acc[4][2];
        #pragma unroll
        for (int m = 0; m < 4; ++m)
            #pragma unroll
            for (int n = 0; n < 2; ++n)
                acc[m][n] = (f32x4){0.f, 0.f, 0.f, 0.f};

        for (int kt = 0; kt < KT; ++kt) {
            int last = (kt + 1 == KT);
            int ncb = last ? cb + 1 : cb;
            int nkt = last ? 0 : kt + 1;
            int havenext = (ncb < 8);
            if (havenext) LOADG(ncb, nkt);   // issue loads; latency hides under compute

            const char* Wb = (const char*)&Wsm[cur][0];
            const char* Zb = (const char*)&Zsm[cur][0];
            #pragma unroll
            for (int ks = 0; ks < 2; ++ks) {
                int kb = ks * 64 + q * 16;
                bf16x8 b[2];
                #pragma unroll
                for (int n = 0; n < 2; ++n) {
                    int rb = wc * 32 + n * 16 + c;
                    b[n] = *(const bf16x8*)(Zb + rb * 128 + (kb ^ ((rb & 7) << 4)));
                }
                #pragma unroll
                for (int m = 0; m < 4; ++m) {
                    int ra = wr * 64 + m * 16 + c;
                    bf16x8 a = *(const bf16x8*)(Wb + ra * 128 + (kb ^ ((ra & 7) << 4)));
                    #pragma unroll
                    for (int n = 0; n < 2; ++n)
                        acc[m][n] = __builtin_amdgcn_mfma_f32_16x16x32_bf16(
                                        a, b[n], acc[m][n], 0, 0, 0);
                }
            }

            if (havenext) WRITES(cur ^ 1);   // vmcnt wait lands here, post-compute
            __syncthreads();                 // drains LDS writes only (cheap)
            cur ^= 1;
        }

        // ---- per-lane branchless top-5 screen (no cross-lane ops) ----
        const int entbase = entchunk + cb * 128 + wr * 64 + q * 4;
        #pragma unroll
        for (int n = 0; n < 2; ++n) {
            #pragma unroll
            for (int m = 0; m < 4; ++m) {
                #pragma unroll
                for (int i = 0; i < 4; ++i) {
                    unsigned u  = __float_as_uint(acc[m][n][i]);
                    unsigned mg = (unsigned)((int)u >> 31);
                    unsigned h  = (u >> 16) ^ (mg | 0x8000u);
                    unsigned p  = (h << 16) | (unsigned)(entbase + m * 16 + i);
                    bool g0 = p > L0[n], g1 = p > L1[n], g2 = p > L2[n],
                         g3 = p > L3[n], g4 = p > L4[n];
                    L4[n] = g4 ? (g3 ? L3[n] : p) : L4[n];
                    L3[n] = g3 ? (g2 ? L2[n] : p) : L3[n];
                    L2[n] = g2 ? (g1 ? L1[n] : p) : L2[n];
                    L1[n] = g1 ? (g0 ? L0[n] : p) : L1[n];
                    L0[n] = g0 ? p : L0[n];
                }
            }
        }
    }

    // write per-lane lists: cand[row][chunk][wr][q][5]
    #pragma unroll
    for (int n = 0; n < 2; ++n) {
        int grow = rowbase + wc * 32 + n * 16 + c;
        unsigned* dst = cand + ((size_t)grow * NCHUNK + blockIdx.x) * CPC + wr * 20 + q * 5;
        dst[0] = L0[n]; dst[1] = L1[n]; dst[2] = L2[n]; dst[3] = L3[n]; dst[4] = L4[n];
    }
}

// ---------------- screen top-24 + exact rescore + softmax + mix + losses ----------------
__global__ __launch_bounds__(256) void k_merge(
    const unsigned* __restrict__ cand,
    const float* __restrict__ w0, const float* __restrict__ rn0,
    const float* __restrict__ w1, const float* __restrict__ rn1,
    const float* __restrict__ rnz0, const float* __restrict__ rnz1,
    const float* __restrict__ z, int zoff, int ld,
    float* __restrict__ outm, float* __restrict__ outs1, float* __restrict__ outs2,
    unsigned int* __restrict__ bitmap, float* __restrict__ lossacc)
{
    const int b = blockIdx.x, tid = threadIdx.x;
    const int lane = tid & 63, wv = tid >> 6;

    __shared__ float zsh[DFULL];
    __shared__ unsigned scand[MRES];
    __shared__ float ssh[MRES];
    __shared__ float wk0[TOPK], wk1[TOPK];
    __shared__ int   ish[TOPK];
    __shared__ float serr[4];

    const float* zrow = z + (size_t)b * DFULL + zoff;
    for (int cc = tid; cc < ld / 4; cc += 256)
        ((float4*)zsh)[cc] = ((const float4*)zrow)[cc];

    // wave 0: top-24 of 640 packed candidates (value-clear extraction)
    if (wv == 0) {
        unsigned creg[10];
        const unsigned* cb_ = cand + (size_t)b * NCAND;
        #pragma unroll
        for (int j = 0; j < 10; ++j) creg[j] = cb_[lane + 64 * j];
        for (int k = 0; k < MRES; ++k) {
            unsigned bv = 0;
            #pragma unroll
            for (int j = 0; j < 10; ++j) bv = (creg[j] > bv) ? creg[j] : bv;
            #pragma unroll
            for (int off = 32; off; off >>= 1) {
                unsigned ov = __shfl_xor(bv, off);
                bv = (ov > bv) ? ov : bv;
            }
            #pragma unroll
            for (int j = 0; j < 10; ++j) if (creg[j] == bv) creg[j] = 0u;
            if (lane == 0) scand[k] = bv;
        }
    }
    __syncthreads();

    // exact f32 rescore of the 24 survivors
    const float rz0 = rnz0[b];
    const float rz1 = w1 ? rnz1[b] : 0.f;
    const float4* z4 = (const float4*)zsh;
    for (int cc = wv; cc < MRES; cc += 4) {
        int idx = scand[cc] & 0xFFFFu;
        const float4* wr0 = (const float4*)(w0 + (size_t)idx * DHALF);
        float d0 = dot4(wr0[lane], z4[lane]) + dot4(wr0[64 + lane], z4[64 + lane]);
        float s = d0 * (rz0 * rn0[idx]);
        if (w1) {
            const float4* wr1 = (const float4*)(w1 + (size_t)idx * DHALF);
            float d1 = dot4(wr1[lane], z4[128 + lane]) + dot4(wr1[64 + lane], z4[192 + lane]);
            s += d1 * (rz1 * rn1[idx]);
        }
        #pragma unroll
        for (int off = 32; off; off >>= 1) s += __shfl_xor(s, off);
        if (lane == 0) ssh[cc] = s;
    }
    __syncthreads();

    // wave 0: exact top-10 of 24 -> softmax weights
    if (wv == 0) {
        float val = (lane < MRES) ? ssh[lane] : -1e30f;
        float vk[TOPK]; int sk[TOPK];
        #pragma unroll
        for (int k = 0; k < TOPK; ++k) {
            float v = val; int who = lane;
            #pragma unroll
            for (int off = 32; off; off >>= 1) {
                float ov = __shfl_xor(v, off);
                int   ow = __shfl_xor(who, off);
                if (ov > v || (ov == v && ow < who)) { v = ov; who = ow; }
            }
            vk[k] = v; sk[k] = who;
            if (lane == who) val = -1e30f;
        }
        if (lane == 0) {
            float vmax = vk[0], e[TOPK], sum = 0.f;
            #pragma unroll
            for (int k = 0; k < TOPK; ++k) { e[k] = expf(2.f * (vk[k] - vmax)); sum += e[k]; }
            #pragma unroll
            for (int k = 0; k < TOPK; ++k) {
                float w = e[k] / sum;
                int idx = scand[sk[k]] & 0xFFFFu;
                ish[k] = idx;
                wk0[k] = w * rn0[idx];
                wk1[k] = w1 ? (w * rn1[idx]) : 0.f;
                atomicOr(&bitmap[idx >> 5], 1u << (idx & 31));
            }
        }
    }
    __syncthreads();

    // mix from ORIGINAL f32 codebook rows, write outputs, loss
    float err = 0.f;
    const int ng = ld / 4;
    for (int g = tid; g < ng; g += 256) {
        int sec = (g >= 128) ? 1 : 0;
        int gl  = g & 127;
        float4 a = {0.f, 0.f, 0.f, 0.f};
        if (sec == 0) {
            #pragma unroll
            for (int k = 0; k < TOPK; ++k) {
                float4 wv4 = ((const float4*)(w0 + (size_t)ish[k] * DHALF))[gl];
                a.x += wk0[k] * wv4.x; a.y += wk0[k] * wv4.y;
                a.z += wk0[k] * wv4.z; a.w += wk0[k] * wv4.w;
            }
        } else {
            #pragma unroll
            for (int k = 0; k < TOPK; ++k) {
                float4 wv4 = ((const float4*)(w1 + (size_t)ish[k] * DHALF))[gl];
                a.x += wk1[k] * wv4.x; a.y += wk1[k] * wv4.y;
                a.z += wk1[k] * wv4.z; a.w += wk1[k] * wv4.w;
            }
        }
        float4 zz = ((const float4*)zsh)[g];
        float dx = a.x - zz.x, dy = a.y - zz.y, dzv = a.z - zz.z, dw = a.w - zz.w;
        err += dx*dx + dy*dy + dzv*dzv + dw*dw;
        ((float4*)(outm + (size_t)b * ld))[g] = a;
        if (outs1) {
            if (sec == 0) ((float4*)(outs1 + (size_t)b * DHALF))[gl] = a;
            else          ((float4*)(outs2 + (size_t)b * DHALF))[gl] = a;
        }
    }
    #pragma unroll
    for (int off = 32; off; off >>= 1) err += __shfl_xor(err, off);
    if (lane == 0) serr[wv] = err;
    __syncthreads();
    if (tid == 0) atomicAdd(lossacc, serr[0] + serr[1] + serr[2] + serr[3]);
}

// ---------------- scalar outputs ----------------
__global__ __launch_bounds__(256) void k_scalars(const unsigned int* __restrict__ bm,
                                                 const float* __restrict__ lossacc,
                                                 float* __restrict__ out)
{
    __shared__ float red[4];
    int tid = threadIdx.x;
    float counts[3];
    for (int g = 0; g < 3; ++g) {
        unsigned c = 0;
        for (int w = tid; w < NE / 32; w += 256) c += __popc(bm[g * (NE / 32) + w]);
        float f = (float)c;
        #pragma unroll
        for (int off = 32; off; off >>= 1) f += __shfl_xor(f, off);
        if ((tid & 63) == 0) red[tid >> 6] = f;
        __syncthreads();
        counts[g] = red[0] + red[1] + red[2] + red[3];
        __syncthreads();
    }
    if (tid == 0) {
        float vq_s = lossacc[0] / (4096.f * 1024.f);
        float vq_t = lossacc[1] / (4096.f * 512.f);
        float vq_g = lossacc[2] / (4096.f * 512.f);
        out[0] = vq_s; out[1] = BETA_C * vq_s;
        out[2] = vq_t; out[3] = BETA_C * vq_t;
        out[4] = vq_g; out[5] = BETA_C * vq_g;
        out[6] = counts[0] / (float)NE;
        out[7] = counts[1] / (float)NE;
        out[8] = counts[2] / (float)NE;
    }
}

// ---------------- host launch ----------------
extern "C" void kernel_launch(void* const* d_in, const int* in_sizes, int n_in,
                              void* d_out, int out_size, void* d_ws, size_t ws_size,
                              hipStream_t stream) {
    const float* z    = (const float*)d_in[0];
    const float* w_t  = (const float*)d_in[1];
    const float* w_g  = (const float*)d_in[2];
    const float* w_st = (const float*)d_in[3];
    const float* w_sg = (const float*)d_in[4];
    float* out = (float*)d_out;

    uint8_t* ws = (uint8_t*)d_ws;
    const size_t OFF_ZN  = 0;                                          // bf16 [4096,1024]
    const size_t OFF_WSH = OFF_ZN  + (size_t)BATCH * DFULL * 2;        // bf16 [16384,1024]
    const size_t OFF_WT  = OFF_WSH + (size_t)NE * DFULL * 2;           // bf16 [16384,512]
    const size_t OFF_WG  = OFF_WT  + (size_t)NE * DHALF * 2;
    const size_t OFF_CD  = OFF_WG  + (size_t)NE * DHALF * 2;           // 3*4096*640 u32
    const size_t OFF_RN  = OFF_CD  + (size_t)3 * BATCH * NCAND * 4;
    const size_t OFF_RNZ = OFF_RN  + (size_t)4 * NE * 4;
    const size_t OFF_BM  = OFF_RNZ + (size_t)2 * BATCH * 4;
    const size_t OFF_LS  = OFF_BM  + (size_t)3 * (NE / 8);

    uint16_t* zn   = (uint16_t*)(ws + OFF_ZN);
    uint16_t* wsh  = (uint16_t*)(ws + OFF_WSH);
    uint16_t* wt   = (uint16_t*)(ws + OFF_WT);
    uint16_t* wg   = (uint16_t*)(ws + OFF_WG);
    unsigned* cd   = (unsigned*)(ws + OFF_CD);
    float*    rnst = (float*)(ws + OFF_RN);
    float*    rnsg = rnst + NE;
    float*    rnt  = rnsg + NE;
    float*    rng  = rnt + NE;
    float*    rnzt = (float*)(ws + OFF_RNZ);
    float*    rnzg = rnzt + BATCH;
    unsigned* bm   = (unsigned*)(ws + OFF_BM);
    float*    ls   = (float*)(ws + OFF_LS);

    hipMemsetAsync(ws + OFF_BM, 0, 3 * (NE / 8) + 64, stream);

    k_norm_z<<<BATCH, 256, 0, stream>>>(z, zn, rnzt, rnzg);
    k_norm_cb<<<NE, 128, 0, stream>>>(w_st, wsh,        DFULL, rnst);
    k_norm_cb<<<NE, 128, 0, stream>>>(w_sg, wsh + 512,  DFULL, rnsg);
    k_norm_cb<<<NE, 128, 0, stream>>>(w_t,  wt,         DHALF, rnt);
    k_norm_cb<<<NE, 128, 0, stream>>>(w_g,  wg,         DHALF, rng);

    const size_t CD1 = (size_t)BATCH * NCAND;
    dim3 gg(NCHUNK, BATCH / 64);
    k_gemm_topk<<<gg, 256, 0, stream>>>(zn, DFULL, 0,   wsh, DFULL, 16, cd);
    k_gemm_topk<<<gg, 256, 0, stream>>>(zn, DFULL, 0,   wt,  DHALF,  8, cd + CD1);
    k_gemm_topk<<<gg, 256, 0, stream>>>(zn, DFULL, 512, wg,  DHALF,  8, cd + 2 * CD1);

    const size_t O1 = (size_t)BATCH * DFULL;
    const size_t O2 = O1 + (size_t)BATCH * DHALF;
    const size_t O3 = O2 + (size_t)BATCH * DHALF;
    const size_t O4 = O3 + (size_t)BATCH * DHALF;
    const size_t O5 = O4 + (size_t)BATCH * DHALF;

    k_merge<<<BATCH, 256, 0, stream>>>(cd,           w_st, rnst, w_sg, rnsg,
                                       rnzt, rnzg, z, 0,   DFULL,
                                       out,      out + O1, out + O2, bm,               ls);
    k_merge<<<BATCH, 256, 0, stream>>>(cd + CD1,     w_t,  rnt,  nullptr, nullptr,
                                       rnzt, nullptr, z, 0,   DHALF,
                                       out + O3, nullptr,  nullptr,  bm + NE / 32,     ls + 1);
    k_merge<<<BATCH, 256, 0, stream>>>(cd + 2 * CD1, w_g,  rng,  nullptr, nullptr,
                                       rnzg, nullptr, z, 512, DHALF,
                                       out + O4, nullptr,  nullptr,  bm + 2 * (NE / 32), ls + 2);

    k_scalars<<<1, 256, 0, stream>>>(bm, ls, out + O5);
}

// Round 9
// 946.352 us; speedup vs baseline: 3.7147x; 3.7147x over previous
//
#include <hip/hip_runtime.h>
#include <stdint.h>

// ---------------- problem constants ----------------
#define NE      16384
#define BATCH   4096
#define DFULL   1024
#define DHALF   512
#define TOPK    10
#define NCHUNK  16
#define CHUNK   1024            // entries per chunk (16384 / 16)
#define CPC     40              // candidates per row per chunk (2 wr * 4 q * 5)
#define NCAND   (NCHUNK * CPC)  // 640 candidates per row
#define MRES    24              // exact-rescore count
#define BETA_C  0.25f

typedef __bf16 bf16x8 __attribute__((ext_vector_type(8)));
typedef float  f32x4  __attribute__((ext_vector_type(4)));

__device__ inline uint16_t f2bf(float f) {
    unsigned u = __float_as_uint(f);
    unsigned r = (u + 0x7FFFu + ((u >> 16) & 1u)) >> 16;
    return (uint16_t)r;
}

__device__ inline float dot4(float4 a, float4 b) {
    return a.x*b.x + a.y*b.y + a.z*b.z + a.w*b.w;
}

// ---------------- normalization kernels ----------------
__global__ __launch_bounds__(256) void k_norm_z(const float* __restrict__ z,
                                                uint16_t* __restrict__ zn,
                                                float* __restrict__ rnzt,
                                                float* __restrict__ rnzg) {
    int b = blockIdx.x, t = threadIdx.x;
    const float4* zp = (const float4*)(z + (size_t)b * DFULL);
    float4 v = zp[t];
    float ss = v.x*v.x + v.y*v.y + v.z*v.z + v.w*v.w;
    #pragma unroll
    for (int off = 32; off; off >>= 1) ss += __shfl_xor(ss, off);
    __shared__ float red[4];
    if ((t & 63) == 0) red[t >> 6] = ss;
    __syncthreads();
    float tot = (t < 128) ? (red[0] + red[1]) : (red[2] + red[3]);
    float rn = rsqrtf(tot + 1e-12f);
    if (t == 0)   rnzt[b] = rn;
    if (t == 128) rnzg[b] = rn;
    uint16_t* o = zn + (size_t)b * DFULL + t * 4;
    o[0] = f2bf(v.x * rn); o[1] = f2bf(v.y * rn);
    o[2] = f2bf(v.z * rn); o[3] = f2bf(v.w * rn);
}

__global__ __launch_bounds__(128) void k_norm_cb(const float* __restrict__ w,
                                                 uint16_t* __restrict__ dst, int dstld,
                                                 float* __restrict__ rns) {
    int r = blockIdx.x, t = threadIdx.x;
    const float4* wp = (const float4*)(w + (size_t)r * DHALF);
    float4 v = wp[t];
    float ss = v.x*v.x + v.y*v.y + v.z*v.z + v.w*v.w;
    #pragma unroll
    for (int off = 32; off; off >>= 1) ss += __shfl_xor(ss, off);
    __shared__ float red[2];
    if ((t & 63) == 0) red[t >> 6] = ss;
    __syncthreads();
    float rn = rsqrtf(red[0] + red[1] + 1e-12f);
    if (t == 0) rns[r] = rn;
    uint16_t* o = dst + (size_t)r * dstld + t * 4;
    o[0] = f2bf(v.x * rn); o[1] = f2bf(v.y * rn);
    o[2] = f2bf(v.z * rn); o[3] = f2bf(v.w * rn);
}

// ---------------- fused GEMM (S^T) + per-lane register top-5 screen ----------
// Block tile: 128 entries x 64 batch, 256 thr = 4 waves. Wave tile 64x32.
// Register-path staging (T14) with NAMED uint4 scalars (R8's lambda-captured
// arrays went to scratch: 2.5 GB/dispatch of scratch writebacks, 3x slowdown).
// Per-thread source/LDS byte offsets depend only on lane/wv -> hoisted.
__global__ __launch_bounds__(256, 3) void k_gemm_topk(
    const uint16_t* __restrict__ Zn, int ldz, int zoff,
    const uint16_t* __restrict__ Wn, int ldw, int KT,
    unsigned* __restrict__ cand)
{
    __shared__ uint16_t Wsm[2][128 * 64];   // entries x k, XOR-swizzled 128B rows (32KB)
    __shared__ uint16_t Zsm[2][64 * 64];    // batch   x k (16KB)

    const int tid  = threadIdx.x;
    const int lane = tid & 63;
    const int wv   = tid >> 6;
    const int wr   = wv >> 1;       // entry half (0..1)
    const int wc   = wv & 1;        // batch half (0..1)
    const int q    = lane >> 4;     // k-group / entry row group
    const int c    = lane & 15;
    const int rowbase  = blockIdx.y * 64;      // batch rows
    const int entchunk = blockIdx.x * CHUNK;   // entry base

    // ---- hoisted per-thread staging offsets (bytes) ----
    // slot i covers LDS bytes [(i*4+wv)*1024 + lane*16 .. +16)
    int so0, so1, so2, so3, so4, so5;      // source offset within panel
    int lo0, lo1, lo2, lo3, lo4, lo5;      // LDS offset within buffer
    {
        int o, row, kb;
        o = (0 * 4 + wv) * 1024 + lane * 16; row = o >> 7; kb = (o & 127) ^ ((row & 7) << 4);
        so0 = row * (ldw * 2) + kb; lo0 = o;
        o = (1 * 4 + wv) * 1024 + lane * 16; row = o >> 7; kb = (o & 127) ^ ((row & 7) << 4);
        so1 = row * (ldw * 2) + kb; lo1 = o;
        o = (2 * 4 + wv) * 1024 + lane * 16; row = o >> 7; kb = (o & 127) ^ ((row & 7) << 4);
        so2 = row * (ldw * 2) + kb; lo2 = o;
        o = (3 * 4 + wv) * 1024 + lane * 16; row = o >> 7; kb = (o & 127) ^ ((row & 7) << 4);
        so3 = row * (ldw * 2) + kb; lo3 = o;
        // Z slots reuse the first two o-patterns but with ldz stride
        o = (0 * 4 + wv) * 1024 + lane * 16; row = o >> 7; kb = (o & 127) ^ ((row & 7) << 4);
        so4 = row * (ldz * 2) + kb; lo4 = o;
        o = (1 * 4 + wv) * 1024 + lane * 16; row = o >> 7; kb = (o & 127) ^ ((row & 7) << 4);
        so5 = row * (ldz * 2) + kb; lo5 = o;
    }

    const char* Wbase = (const char*)Wn;
    const char* Zbase = (const char*)(Zn + zoff);

    // per-lane sorted lists (descending), packed (sortable16(v)<<16)|entry_idx
    unsigned La0 = 0, La1 = 0, La2 = 0, La3 = 0, La4 = 0;   // batch row n=0
    unsigned Lb0 = 0, Lb1 = 0, Lb2 = 0, Lb3 = 0, Lb4 = 0;   // batch row n=1

    // named staging registers (6 x uint4 = 24 VGPR, never in memory)
    uint4 sw0, sw1, sw2, sw3, sz0, sz1;

#define LOADG(cb2, kt2) {                                                           \
        const char* Wg = Wbase + ((size_t)(entchunk + (cb2) * 128) * ldw + (kt2) * 64) * 2; \
        const char* Zg = Zbase + ((size_t)rowbase * ldz + (kt2) * 64) * 2;          \
        sw0 = *(const uint4*)(Wg + so0);                                            \
        sw1 = *(const uint4*)(Wg + so1);                                            \
        sw2 = *(const uint4*)(Wg + so2);                                            \
        sw3 = *(const uint4*)(Wg + so3);                                            \
        sz0 = *(const uint4*)(Zg + so4);                                            \
        sz1 = *(const uint4*)(Zg + so5);                                            \
    }
#define WRITES(bufi) {                                                              \
        char* Wd = (char*)&Wsm[bufi][0];                                            \
        char* Zd = (char*)&Zsm[bufi][0];                                            \
        *(uint4*)(Wd + lo0) = sw0;                                                  \
        *(uint4*)(Wd + lo1) = sw1;                                                  \
        *(uint4*)(Wd + lo2) = sw2;                                                  \
        *(uint4*)(Wd + lo3) = sw3;                                                  \
        *(uint4*)(Zd + lo4) = sz0;                                                  \
        *(uint4*)(Zd + lo5) = sz1;                                                  \
    }

    LOADG(0, 0);
    WRITES(0);
    __syncthreads();
    int cur = 0;

    for (int cb = 0; cb < 8; ++cb) {
        f32x4 acc[4][2];
        #pragma unroll
        for (int m = 0; m < 4; ++m)
            #pragma unroll
            for (int n = 0; n < 2; ++n)
                acc[m][n] = (f32x4){0.f, 0.f, 0.f, 0.f};

        for (int kt = 0; kt < KT; ++kt) {
            int last = (kt + 1 == KT);
            int ncb = last ? cb + 1 : cb;
            int nkt = last ? 0 : kt + 1;
            int havenext = (ncb < 8);
            if (havenext) LOADG(ncb, nkt);   // issue loads; latency hides under compute

            const char* Wb = (const char*)&Wsm[cur][0];
            const char* Zb = (const char*)&Zsm[cur][0];
            #pragma unroll
            for (int ks = 0; ks < 2; ++ks) {
                int kb = ks * 64 + q * 16;
                bf16x8 b[2];
                #pragma unroll
                for (int n = 0; n < 2; ++n) {
                    int rb = wc * 32 + n * 16 + c;
                    b[n] = *(const bf16x8*)(Zb + rb * 128 + (kb ^ ((rb & 7) << 4)));
                }
                #pragma unroll
                for (int m = 0; m < 4; ++m) {
                    int ra = wr * 64 + m * 16 + c;
                    bf16x8 a = *(const bf16x8*)(Wb + ra * 128 + (kb ^ ((ra & 7) << 4)));
                    #pragma unroll
                    for (int n = 0; n < 2; ++n)
                        acc[m][n] = __builtin_amdgcn_mfma_f32_16x16x32_bf16(
                                        a, b[n], acc[m][n], 0, 0, 0);
                }
            }

            if (havenext) WRITES(cur ^ 1);   // vmcnt wait lands here, post-compute
            __syncthreads();                 // drains LDS writes only (cheap)
            cur ^= 1;
        }

        // ---- per-lane branchless top-5 screen (no cross-lane ops) ----
        const int entbase = entchunk + cb * 128 + wr * 64 + q * 4;
        #pragma unroll
        for (int n = 0; n < 2; ++n) {
            #pragma unroll
            for (int m = 0; m < 4; ++m) {
                #pragma unroll
                for (int i = 0; i < 4; ++i) {
                    unsigned u  = __float_as_uint(acc[m][n][i]);
                    unsigned mg = (unsigned)((int)u >> 31);
                    unsigned h  = (u >> 16) ^ (mg | 0x8000u);
                    unsigned p  = (h << 16) | (unsigned)(entbase + m * 16 + i);
                    if (n == 0) {
                        bool g0 = p > La0, g1 = p > La1, g2 = p > La2,
                             g3 = p > La3, g4 = p > La4;
                        La4 = g4 ? (g3 ? La3 : p) : La4;
                        La3 = g3 ? (g2 ? La2 : p) : La3;
                        La2 = g2 ? (g1 ? La1 : p) : La2;
                        La1 = g1 ? (g0 ? La0 : p) : La1;
                        La0 = g0 ? p : La0;
                    } else {
                        bool g0 = p > Lb0, g1 = p > Lb1, g2 = p > Lb2,
                             g3 = p > Lb3, g4 = p > Lb4;
                        Lb4 = g4 ? (g3 ? Lb3 : p) : Lb4;
                        Lb3 = g3 ? (g2 ? Lb2 : p) : Lb3;
                        Lb2 = g2 ? (g1 ? Lb1 : p) : Lb2;
                        Lb1 = g1 ? (g0 ? Lb0 : p) : Lb1;
                        Lb0 = g0 ? p : Lb0;
                    }
                }
            }
        }
    }

    // write per-lane lists: cand[row][chunk][wr][q][5]
    {
        int grow = rowbase + wc * 32 + 0 * 16 + c;
        unsigned* dst = cand + ((size_t)grow * NCHUNK + blockIdx.x) * CPC + wr * 20 + q * 5;
        dst[0] = La0; dst[1] = La1; dst[2] = La2; dst[3] = La3; dst[4] = La4;
        grow = rowbase + wc * 32 + 1 * 16 + c;
        dst = cand + ((size_t)grow * NCHUNK + blockIdx.x) * CPC + wr * 20 + q * 5;
        dst[0] = Lb0; dst[1] = Lb1; dst[2] = Lb2; dst[3] = Lb3; dst[4] = Lb4;
    }
#undef LOADG
#undef WRITES
}

// ---------------- screen top-24 + exact rescore + softmax + mix + losses ----------------
__global__ __launch_bounds__(256) void k_merge(
    const unsigned* __restrict__ cand,
    const float* __restrict__ w0, const float* __restrict__ rn0,
    const float* __restrict__ w1, const float* __restrict__ rn1,
    const float* __restrict__ rnz0, const float* __restrict__ rnz1,
    const float* __restrict__ z, int zoff, int ld,
    float* __restrict__ outm, float* __restrict__ outs1, float* __restrict__ outs2,
    unsigned int* __restrict__ bitmap, float* __restrict__ lossacc)
{
    const int b = blockIdx.x, tid = threadIdx.x;
    const int lane = tid & 63, wv = tid >> 6;

    __shared__ float zsh[DFULL];
    __shared__ unsigned scand[MRES];
    __shared__ float ssh[MRES];
    __shared__ float wk0[TOPK], wk1[TOPK];
    __shared__ int   ish[TOPK];
    __shared__ float serr[4];

    const float* zrow = z + (size_t)b * DFULL + zoff;
    for (int cc = tid; cc < ld / 4; cc += 256)
        ((float4*)zsh)[cc] = ((const float4*)zrow)[cc];

    // wave 0: top-24 of 640 packed candidates (value-clear extraction)
    if (wv == 0) {
        unsigned creg[10];
        const unsigned* cb_ = cand + (size_t)b * NCAND;
        #pragma unroll
        for (int j = 0; j < 10; ++j) creg[j] = cb_[lane + 64 * j];
        for (int k = 0; k < MRES; ++k) {
            unsigned bv = 0;
            #pragma unroll
            for (int j = 0; j < 10; ++j) bv = (creg[j] > bv) ? creg[j] : bv;
            #pragma unroll
            for (int off = 32; off; off >>= 1) {
                unsigned ov = __shfl_xor(bv, off);
                bv = (ov > bv) ? ov : bv;
            }
            #pragma unroll
            for (int j = 0; j < 10; ++j) if (creg[j] == bv) creg[j] = 0u;
            if (lane == 0) scand[k] = bv;
        }
    }
    __syncthreads();

    // exact f32 rescore of the 24 survivors
    const float rz0 = rnz0[b];
    const float rz1 = w1 ? rnz1[b] : 0.f;
    const float4* z4 = (const float4*)zsh;
    for (int cc = wv; cc < MRES; cc += 4) {
        int idx = scand[cc] & 0xFFFFu;
        const float4* wr0 = (const float4*)(w0 + (size_t)idx * DHALF);
        float d0 = dot4(wr0[lane], z4[lane]) + dot4(wr0[64 + lane], z4[64 + lane]);
        float s = d0 * (rz0 * rn0[idx]);
        if (w1) {
            const float4* wr1 = (const float4*)(w1 + (size_t)idx * DHALF);
            float d1 = dot4(wr1[lane], z4[128 + lane]) + dot4(wr1[64 + lane], z4[192 + lane]);
            s += d1 * (rz1 * rn1[idx]);
        }
        #pragma unroll
        for (int off = 32; off; off >>= 1) s += __shfl_xor(s, off);
        if (lane == 0) ssh[cc] = s;
    }
    __syncthreads();

    // wave 0: exact top-10 of 24 -> softmax weights
    if (wv == 0) {
        float val = (lane < MRES) ? ssh[lane] : -1e30f;
        float vk[TOPK]; int sk[TOPK];
        #pragma unroll
        for (int k = 0; k < TOPK; ++k) {
            float v = val; int who = lane;
            #pragma unroll
            for (int off = 32; off; off >>= 1) {
                float ov = __shfl_xor(v, off);
                int   ow = __shfl_xor(who, off);
                if (ov > v || (ov == v && ow < who)) { v = ov; who = ow; }
            }
            vk[k] = v; sk[k] = who;
            if (lane == who) val = -1e30f;
        }
        if (lane == 0) {
            float vmax = vk[0], e[TOPK], sum = 0.f;
            #pragma unroll
            for (int k = 0; k < TOPK; ++k) { e[k] = expf(2.f * (vk[k] - vmax)); sum += e[k]; }
            #pragma unroll
            for (int k = 0; k < TOPK; ++k) {
                float w = e[k] / sum;
                int idx = scand[sk[k]] & 0xFFFFu;
                ish[k] = idx;
                wk0[k] = w * rn0[idx];
                wk1[k] = w1 ? (w * rn1[idx]) : 0.f;
                atomicOr(&bitmap[idx >> 5], 1u << (idx & 31));
            }
        }
    }
    __syncthreads();

    // mix from ORIGINAL f32 codebook rows, write outputs, loss
    float err = 0.f;
    const int ng = ld / 4;
    for (int g = tid; g < ng; g += 256) {
        int sec = (g >= 128) ? 1 : 0;
        int gl  = g & 127;
        float4 a = {0.f, 0.f, 0.f, 0.f};
        if (sec == 0) {
            #pragma unroll
            for (int k = 0; k < TOPK; ++k) {
                float4 wv4 = ((const float4*)(w0 + (size_t)ish[k] * DHALF))[gl];
                a.x += wk0[k] * wv4.x; a.y += wk0[k] * wv4.y;
                a.z += wk0[k] * wv4.z; a.w += wk0[k] * wv4.w;
            }
        } else {
            #pragma unroll
            for (int k = 0; k < TOPK; ++k) {
                float4 wv4 = ((const float4*)(w1 + (size_t)ish[k] * DHALF))[gl];
                a.x += wk1[k] * wv4.x; a.y += wk1[k] * wv4.y;
                a.z += wk1[k] * wv4.z; a.w += wk1[k] * wv4.w;
            }
        }
        float4 zz = ((const float4*)zsh)[g];
        float dx = a.x - zz.x, dy = a.y - zz.y, dzv = a.z - zz.z, dw = a.w - zz.w;
        err += dx*dx + dy*dy + dzv*dzv + dw*dw;
        ((float4*)(outm + (size_t)b * ld))[g] = a;
        if (outs1) {
            if (sec == 0) ((float4*)(outs1 + (size_t)b * DHALF))[gl] = a;
            else          ((float4*)(outs2 + (size_t)b * DHALF))[gl] = a;
        }
    }
    #pragma unroll
    for (int off = 32; off; off >>= 1) err += __shfl_xor(err, off);
    if (lane == 0) serr[wv] = err;
    __syncthreads();
    if (tid == 0) atomicAdd(lossacc, serr[0] + serr[1] + serr[2] + serr[3]);
}

// ---------------- scalar outputs ----------------
__global__ __launch_bounds__(256) void k_scalars(const unsigned int* __restrict__ bm,
                                                 const float* __restrict__ lossacc,
                                                 float* __restrict__ out)
{
    __shared__ float red[4];
    int tid = threadIdx.x;
    float counts[3];
    for (int g = 0; g < 3; ++g) {
        unsigned c = 0;
        for (int w = tid; w < NE / 32; w += 256) c += __popc(bm[g * (NE / 32) + w]);
        float f = (float)c;
        #pragma unroll
        for (int off = 32; off; off >>= 1) f += __shfl_xor(f, off);
        if ((tid & 63) == 0) red[tid >> 6] = f;
        __syncthreads();
        counts[g] = red[0] + red[1] + red[2] + red[3];
        __syncthreads();
    }
    if (tid == 0) {
        float vq_s = lossacc[0] / (4096.f * 1024.f);
        float vq_t = lossacc[1] / (4096.f * 512.f);
        float vq_g = lossacc[2] / (4096.f * 512.f);
        out[0] = vq_s; out[1] = BETA_C * vq_s;
        out[2] = vq_t; out[3] = BETA_C * vq_t;
        out[4] = vq_g; out[5] = BETA_C * vq_g;
        out[6] = counts[0] / (float)NE;
        out[7] = counts[1] / (float)NE;
        out[8] = counts[2] / (float)NE;
    }
}

// ---------------- host launch ----------------
extern "C" void kernel_launch(void* const* d_in, const int* in_sizes, int n_in,
                              void* d_out, int out_size, void* d_ws, size_t ws_size,
                              hipStream_t stream) {
    const float* z    = (const float*)d_in[0];
    const float* w_t  = (const float*)d_in[1];
    const float* w_g  = (const float*)d_in[2];
    const float* w_st = (const float*)d_in[3];
    const float* w_sg = (const float*)d_in[4];
    float* out = (float*)d_out;

    uint8_t* ws = (uint8_t*)d_ws;
    const size_t OFF_ZN  = 0;                                          // bf16 [4096,1024]
    const size_t OFF_WSH = OFF_ZN  + (size_t)BATCH * DFULL * 2;        // bf16 [16384,1024]
    const size_t OFF_WT  = OFF_WSH + (size_t)NE * DFULL * 2;           // bf16 [16384,512]
    const size_t OFF_WG  = OFF_WT  + (size_t)NE * DHALF * 2;
    const size_t OFF_CD  = OFF_WG  + (size_t)NE * DHALF * 2;           // 3*4096*640 u32
    const size_t OFF_RN  = OFF_CD  + (size_t)3 * BATCH * NCAND * 4;
    const size_t OFF_RNZ = OFF_RN  + (size_t)4 * NE * 4;
    const size_t OFF_BM  = OFF_RNZ + (size_t)2 * BATCH * 4;
    const size_t OFF_LS  = OFF_BM  + (size_t)3 * (NE / 8);

    uint16_t* zn   = (uint16_t*)(ws + OFF_ZN);
    uint16_t* wsh  = (uint16_t*)(ws + OFF_WSH);
    uint16_t* wt   = (uint16_t*)(ws + OFF_WT);
    uint16_t* wg   = (uint16_t*)(ws + OFF_WG);
    unsigned* cd   = (unsigned*)(ws + OFF_CD);
    float*    rnst = (float*)(ws + OFF_RN);
    float*    rnsg = rnst + NE;
    float*    rnt  = rnsg + NE;
    float*    rng  = rnt + NE;
    float*    rnzt = (float*)(ws + OFF_RNZ);
    float*    rnzg = rnzt + BATCH;
    unsigned* bm   = (unsigned*)(ws + OFF_BM);
    float*    ls   = (float*)(ws + OFF_LS);

    hipMemsetAsync(ws + OFF_BM, 0, 3 * (NE / 8) + 64, stream);

    k_norm_z<<<BATCH, 256, 0, stream>>>(z, zn, rnzt, rnzg);
    k_norm_cb<<<NE, 128, 0, stream>>>(w_st, wsh,        DFULL, rnst);
    k_norm_cb<<<NE, 128, 0, stream>>>(w_sg, wsh + 512,  DFULL, rnsg);
    k_norm_cb<<<NE, 128, 0, stream>>>(w_t,  wt,         DHALF, rnt);
    k_norm_cb<<<NE, 128, 0, stream>>>(w_g,  wg,         DHALF, rng);

    const size_t CD1 = (size_t)BATCH * NCAND;
    dim3 gg(NCHUNK, BATCH / 64);
    k_gemm_topk<<<gg, 256, 0, stream>>>(zn, DFULL, 0,   wsh, DFULL, 16, cd);
    k_gemm_topk<<<gg, 256, 0, stream>>>(zn, DFULL, 0,   wt,  DHALF,  8, cd + CD1);
    k_gemm_topk<<<gg, 256, 0, stream>>>(zn, DFULL, 512, wg,  DHALF,  8, cd + 2 * CD1);

    const size_t O1 = (size_t)BATCH * DFULL;
    const size_t O2 = O1 + (size_t)BATCH * DHALF;
    const size_t O3 = O2 + (size_t)BATCH * DHALF;
    const size_t O4 = O3 + (size_t)BATCH * DHALF;
    const size_t O5 = O4 + (size_t)BATCH * DHALF;

    k_merge<<<BATCH, 256, 0, stream>>>(cd,           w_st, rnst, w_sg, rnsg,
                                       rnzt, rnzg, z, 0,   DFULL,
                                       out,      out + O1, out + O2, bm,               ls);
    k_merge<<<BATCH, 256, 0, stream>>>(cd + CD1,     w_t,  rnt,  nullptr, nullptr,
                                       rnzt, nullptr, z, 0,   DHALF,
                                       out + O3, nullptr,  nullptr,  bm + NE / 32,     ls + 1);
    k_merge<<<BATCH, 256, 0, stream>>>(cd + 2 * CD1, w_g,  rng,  nullptr, nullptr,
                                       rnzg, nullptr, z, 512, DHALF,
                                       out + O4, nullptr,  nullptr,  bm + 2 * (NE / 32), ls + 2);

    k_scalars<<<1, 256, 0, stream>>>(bm, ls, out + O5);
}